// Round 2
// baseline (4466.322 us; speedup 1.0000x reference)
//
#include <hip/hip_runtime.h>
#include <math.h>

#define S_LEN 2048
#define HD    64
#define QT    16      // query rows per block
#define NT    512     // threads per block
#define NW    8       // waves per block
#define CAP   512     // candidate capacity per row
#define NITER 50      // entmax bisection iterations (reference default)

__device__ __forceinline__ float wave_max(float v) {
#pragma unroll
    for (int off = 32; off >= 1; off >>= 1)
        v = fmaxf(v, __shfl_xor(v, off, 64));
    return v;
}

__device__ __forceinline__ float wave_sum(float v) {
#pragma unroll
    for (int off = 32; off >= 1; off >>= 1)
        v += __shfl_xor(v, off, 64);
    return v;
}

__device__ __forceinline__ float pfun_t(float t, float inv, bool inv2) {
    float u = fmaxf(t, 0.0f);
    return inv2 ? u * u : powf(u, inv);
}

// Register-resident bisection over <= NR*64 candidates held in LDS row cvrow.
template <int NR>
__device__ __forceinline__ void bisect_reg(const float* cvrow, int ncp, int lane,
                                           float tau_lo0, float tau_hi,
                                           float inv, bool inv2,
                                           float& tau_out, float& isum_out) {
    float c[NR];
#pragma unroll
    for (int j = 0; j < NR; ++j) {
        int i = lane + 64 * j;
        c[j] = (i < ncp) ? cvrow[i] : -3.0e38f;
    }
    float tau = tau_lo0;
    float s0 = 0.0f;
#pragma unroll
    for (int j = 0; j < NR; ++j) s0 += pfun_t(c[j] - tau, inv, inv2);
    const float f_lo = wave_sum(s0) - 1.0f;
    float dm = tau_hi - tau_lo0;
    for (int it = 0; it < NITER; ++it) {
        dm *= 0.5f;
        float tm = tau + dm;
        float s = 0.0f;
#pragma unroll
        for (int j = 0; j < NR; ++j) s += pfun_t(c[j] - tm, inv, inv2);
        float fm = wave_sum(s) - 1.0f;
        if (fm * f_lo >= 0.0f) tau = tm;
    }
    float s = 0.0f;
#pragma unroll
    for (int j = 0; j < NR; ++j) s += pfun_t(c[j] - tau, inv, inv2);
    float ssum = wave_sum(s);
    tau_out = tau;
    isum_out = 1.0f / ssum;
}

// waves_per_eu(4,4): pin allocator to 128-VGPR budget (4 waves/EU = 16 waves/CU
// = 2 blocks/CU). Round-1 let the heuristic target 8 waves/EU -> 64 VGPRs ->
// xa[16][4] spilled to scratch (WRITE_SIZE 3.4 GB vs 1.1 GB semantic).
__global__ __attribute__((amdgpu_waves_per_eu(4, 4))) __launch_bounds__(NT)
void entmax_attn(const float* __restrict__ Qp, const float* __restrict__ Kp,
                 const float* __restrict__ Vp, const float* __restrict__ alphap,
                 float* __restrict__ outp, float* __restrict__ pattn) {
    __shared__ float          candv[QT][CAP];
    __shared__ unsigned short candi[QT][CAP];
    __shared__ int            ncnt[QT];
    __shared__ float          rmax8[QT][NW];
    __shared__ float          rmxf[QT];
    __shared__ float          taus[QT];
    __shared__ float          isums[QT];
    __shared__ float          redw[NW];

    const int tid  = threadIdx.x;
    const int wv   = tid >> 6;
    const int lane = tid & 63;
    const int bh   = blockIdx.y;
    const int q0   = blockIdx.x * QT;

    const float alpha = alphap[0];
    const float am1   = alpha - 1.0f;
    const float inv   = 1.0f / am1;
    const bool  inv2  = (inv == 2.0f);
    const float xscale = (1.0f / sqrtf((float)HD)) * am1;   // fold score scale * (alpha-1)
    const float gp_d   = powf(1.0f / (float)S_LEN, am1);    // _gp(1/d, alpha)

    if (tid < QT) ncnt[tid] = 0;

    const float* qbase = Qp + ((size_t)bh * S_LEN + q0) * HD;
    const float* kbase = Kp + (size_t)bh * S_LEN * HD;
    const float* vbase = Vp + (size_t)bh * S_LEN * HD;

    // ---- Phase 1: Xa = (Q.K^T * scale * (alpha-1)) held in registers ----
    // kv chunk = 2 key rows (16 regs) to stay under the 128-VGPR budget.
    float xa[QT][4];
#pragma unroll
    for (int r = 0; r < QT; ++r)
#pragma unroll
        for (int kk = 0; kk < 4; ++kk) xa[r][kk] = 0.0f;

    for (int dc = 0; dc < 8; ++dc) {
#pragma unroll
        for (int kp = 0; kp < 2; ++kp) {
            float kv[2][8];
#pragma unroll
            for (int k2 = 0; k2 < 2; ++k2) {
                const float* kptr = kbase + ((size_t)((kp * 2 + k2) * NT + tid)) * HD + dc * 8;
                float4 a = *(const float4*)kptr;
                float4 b = *(const float4*)(kptr + 4);
                kv[k2][0] = a.x; kv[k2][1] = a.y; kv[k2][2] = a.z; kv[k2][3] = a.w;
                kv[k2][4] = b.x; kv[k2][5] = b.y; kv[k2][6] = b.z; kv[k2][7] = b.w;
            }
#pragma unroll
            for (int r = 0; r < QT; ++r) {
                const float* qp = qbase + r * HD + dc * 8;  // wave-uniform -> s_load
                float4 qa = *(const float4*)qp;
                float4 qb = *(const float4*)(qp + 4);
                float qv[8] = {qa.x, qa.y, qa.z, qa.w, qb.x, qb.y, qb.z, qb.w};
#pragma unroll
                for (int k2 = 0; k2 < 2; ++k2) {
                    float a0 = xa[r][kp * 2 + k2];
#pragma unroll
                    for (int j = 0; j < 8; ++j) a0 = fmaf(qv[j], kv[k2][j], a0);
                    xa[r][kp * 2 + k2] = a0;
                }
            }
        }
    }
#pragma unroll
    for (int r = 0; r < QT; ++r)
#pragma unroll
        for (int kk = 0; kk < 4; ++kk) xa[r][kk] *= xscale;

    // ---- Phase 2: exact row maxes ----
#pragma unroll
    for (int r = 0; r < QT; ++r) {
        float pm = fmaxf(fmaxf(xa[r][0], xa[r][1]), fmaxf(xa[r][2], xa[r][3]));
        pm = wave_max(pm);
        if (lane == 0) rmax8[r][wv] = pm;
    }
    __syncthreads();
    if (tid < QT) {
        float m = rmax8[tid][0];
#pragma unroll
        for (int w = 1; w < NW; ++w) m = fmaxf(m, rmax8[tid][w]);
        rmxf[tid] = m;
    }
    __syncthreads();

    // ---- Phase 3: candidate compaction (Xa > tau_lo0 can ever be nonzero) ----
#pragma unroll
    for (int r = 0; r < QT; ++r) {
        const float tl0 = rmxf[r] - 1.0f;
#pragma unroll
        for (int kk = 0; kk < 4; ++kk) {
            const float v = xa[r][kk];
            const bool pred = (v > tl0);
            unsigned long long m = __ballot(pred);
            int base = 0;
            if (lane == 0 && m) base = atomicAdd(&ncnt[r], __popcll(m));
            base = __shfl(base, 0, 64);
            if (pred) {
                int pos = base + __popcll(m & ((1ull << lane) - 1ull));
                if (pos < CAP) {
                    candv[r][pos] = v;
                    candi[r][pos] = (unsigned short)(kk * NT + tid);
                }
            }
        }
    }
    __syncthreads();

    // ---- Phase 4: per-wave bisection (wave w owns rows w and w+8) ----
    for (int rr = 0; rr < QT / NW; ++rr) {
        const int row = wv + rr * NW;
        const int nc = ncnt[row];
        if (nc <= CAP) {
            const int ncp = (nc + 7) & ~7;
            for (int i = nc + lane; i < ncp; i += 64) {  // pad to multiple of 8
                candv[row][i] = -3.0e38f;
                candi[row][i] = 0;
            }
            const float mx  = rmxf[row];
            const float tl0 = mx - 1.0f;
            const float th  = mx - gp_d;
            float tau, isum;
            if (ncp <= 256) bisect_reg<4>(&candv[row][0], ncp, lane, tl0, th, inv, inv2, tau, isum);
            else            bisect_reg<8>(&candv[row][0], ncp, lane, tl0, th, inv, inv2, tau, isum);
            if (lane == 0) { taus[row] = tau; isums[row] = isum; }
        }
    }

    // ---- Phase 4b: block-wide fallback for overflow rows (nc > CAP; rare) ----
#pragma unroll
    for (int r = 0; r < QT; ++r) {
        if (ncnt[r] > CAP) {   // uniform condition -> barriers are safe
            const float mx = rmxf[r];
            float tau = mx - 1.0f;
            float s0 = 0.0f;
#pragma unroll
            for (int kk = 0; kk < 4; ++kk) s0 += pfun_t(xa[r][kk] - tau, inv, inv2);
            s0 = wave_sum(s0);
            if (lane == 0) redw[wv] = s0;
            __syncthreads();
            float f_lo = redw[0] + redw[1] + redw[2] + redw[3] +
                         redw[4] + redw[5] + redw[6] + redw[7] - 1.0f;
            __syncthreads();
            float dm = (mx - gp_d) - tau;
            for (int it = 0; it < NITER; ++it) {
                dm *= 0.5f;
                float tm = tau + dm;
                float s = 0.0f;
#pragma unroll
                for (int kk = 0; kk < 4; ++kk) s += pfun_t(xa[r][kk] - tm, inv, inv2);
                s = wave_sum(s);
                if (lane == 0) redw[wv] = s;
                __syncthreads();
                float fm = redw[0] + redw[1] + redw[2] + redw[3] +
                           redw[4] + redw[5] + redw[6] + redw[7] - 1.0f;
                __syncthreads();
                if (fm * f_lo >= 0.0f) tau = tm;
            }
            float s = 0.0f;
#pragma unroll
            for (int kk = 0; kk < 4; ++kk) s += pfun_t(xa[r][kk] - tau, inv, inv2);
            s = wave_sum(s);
            if (lane == 0) redw[wv] = s;
            __syncthreads();
            float ssum = redw[0] + redw[1] + redw[2] + redw[3] +
                         redw[4] + redw[5] + redw[6] + redw[7];
            __syncthreads();
            if (tid == 0) { taus[r] = tau; isums[r] = 1.0f / ssum; }
        }
    }
    __syncthreads();

    // ---- Phase 5: write normalized p_attn (all S entries incl. zeros) ----
    const size_t prow_base = ((size_t)bh * S_LEN + q0) * S_LEN;
#pragma unroll
    for (int r = 0; r < QT; ++r) {
        const float tau  = taus[r];
        const float isum = isums[r];
        float* prow = pattn + prow_base + (size_t)r * S_LEN;
#pragma unroll
        for (int kk = 0; kk < 4; ++kk) {
            float p = pfun_t(xa[r][kk] - tau, inv, inv2) * isum;
            prow[kk * NT + tid] = p;
        }
    }
    __threadfence_block();
    __syncthreads();

    // ---- Phase 6: out = p @ V, sparse over candidates (lane == d) ----
    for (int rr = 0; rr < QT / NW; ++rr) {
        const int row  = wv + rr * NW;
        const int qrow = q0 + row;
        const int nc   = ncnt[row];
        const float tau  = taus[row];
        const float isum = isums[row];
        float oacc = 0.0f;
        if (nc <= CAP) {
            const int ncp = (nc + 7) & ~7;
            for (int i = lane; i < ncp; i += 64)  // candv := unnormalized p
                candv[row][i] = pfun_t(candv[row][i] - tau, inv, inv2);
            for (int i = 0; i < ncp; i += 8) {
#pragma unroll
                for (int u = 0; u < 8; ++u) {
                    oacc = fmaf(candv[row][i + u],
                                vbase[(size_t)candi[row][i + u] * HD + lane], oacc);
                }
            }
            oacc *= isum;
        } else {
            // read back normalized p from global (written above, fenced)
            const float* prow = pattn + ((size_t)bh * S_LEN + qrow) * S_LEN;
            for (int k = 0; k < S_LEN; ++k)
                oacc = fmaf(prow[k], vbase[(size_t)k * HD + lane], oacc);
        }
        outp[((size_t)bh * S_LEN + qrow) * HD + lane] = oacc;
    }
}

extern "C" void kernel_launch(void* const* d_in, const int* in_sizes, int n_in,
                              void* d_out, int out_size, void* d_ws, size_t ws_size,
                              hipStream_t stream) {
    const float* Q = (const float*)d_in[0];
    const float* K = (const float*)d_in[1];
    const float* V = (const float*)d_in[2];
    const float* A = (const float*)d_in[3];
    float* out = (float*)d_out;
    const int BH = in_sizes[0] / (S_LEN * HD);          // 64
    float* p = out + (size_t)BH * S_LEN * HD;           // p_attn follows out
    dim3 grid(S_LEN / QT, BH);
    entmax_attn<<<grid, NT, 0, stream>>>(Q, K, V, A, out, p);
}

// Round 3
// 3661.608 us; speedup vs baseline: 1.2198x; 1.2198x over previous
//
#include <hip/hip_runtime.h>
#include <math.h>

#define S_LEN 2048
#define HD    64
#define QT    8       // query rows per block (QT*4 floats of scores per thread -> fits 64 VGPRs)
#define NT    512     // threads per block
#define NW    8       // waves per block
#define CAP   512     // candidate capacity per row
#define NITER 50      // entmax bisection iterations (reference default)

__device__ __forceinline__ float wave_max(float v) {
#pragma unroll
    for (int off = 32; off >= 1; off >>= 1)
        v = fmaxf(v, __shfl_xor(v, off, 64));
    return v;
}

__device__ __forceinline__ float wave_sum(float v) {
#pragma unroll
    for (int off = 32; off >= 1; off >>= 1)
        v += __shfl_xor(v, off, 64);
    return v;
}

__device__ __forceinline__ float pfun_t(float t, float inv, bool inv2) {
    float u = fmaxf(t, 0.0f);
    return inv2 ? u * u : powf(u, inv);
}

// Register-resident bisection over <= NR*64 candidates held in LDS row cvrow.
template <int NR>
__device__ __forceinline__ void bisect_reg(const float* cvrow, int ncp, int lane,
                                           float tau_lo0, float tau_hi,
                                           float inv, bool inv2,
                                           float& tau_out, float& isum_out) {
    float c[NR];
#pragma unroll
    for (int j = 0; j < NR; ++j) {
        int i = lane + 64 * j;
        c[j] = (i < ncp) ? cvrow[i] : -3.0e38f;
    }
    float tau = tau_lo0;
    float s0 = 0.0f;
#pragma unroll
    for (int j = 0; j < NR; ++j) s0 += pfun_t(c[j] - tau, inv, inv2);
    const float f_lo = wave_sum(s0) - 1.0f;
    float dm = tau_hi - tau_lo0;
    for (int it = 0; it < NITER; ++it) {
        dm *= 0.5f;
        float tm = tau + dm;
        float s = 0.0f;
#pragma unroll
        for (int j = 0; j < NR; ++j) s += pfun_t(c[j] - tm, inv, inv2);
        float fm = wave_sum(s) - 1.0f;
        if (fm * f_lo >= 0.0f) tau = tm;
    }
    float s = 0.0f;
#pragma unroll
    for (int j = 0; j < NR; ++j) s += pfun_t(c[j] - tau, inv, inv2);
    float ssum = wave_sum(s);
    tau_out = tau;
    isum_out = 1.0f / ssum;
}

// QT=8: xa[8][4]=32 VGPR + kb[8]=8 + addressing fits the 64-VGPR max-occupancy
// budget the allocator insists on (R1/R2: occupancy attributes ignored, xa[16][4]
// spilled -> 3.3/10.6 GB scratch WRITE_SIZE). Q loads are wave-uniform -> SGPRs.
__global__ __launch_bounds__(NT)
void entmax_attn(const float* __restrict__ Qp, const float* __restrict__ Kp,
                 const float* __restrict__ Vp, const float* __restrict__ alphap,
                 float* __restrict__ outp, float* __restrict__ pattn) {
    __shared__ float          candv[QT][CAP];
    __shared__ unsigned short candi[QT][CAP];
    __shared__ int            ncnt[QT];
    __shared__ float          rmax8[QT][NW];
    __shared__ float          rmxf[QT];
    __shared__ float          taus[QT];
    __shared__ float          isums[QT];
    __shared__ float          redw[NW];

    const int tid  = threadIdx.x;
    const int wv   = tid >> 6;
    const int lane = tid & 63;
    const int bh   = blockIdx.y;
    const int q0   = blockIdx.x * QT;

    const float alpha = alphap[0];
    const float am1   = alpha - 1.0f;
    const float inv   = 1.0f / am1;
    const bool  inv2  = (inv == 2.0f);
    const float xscale = (1.0f / sqrtf((float)HD)) * am1;   // fold score scale * (alpha-1)
    const float gp_d   = powf(1.0f / (float)S_LEN, am1);    // _gp(1/d, alpha)

    if (tid < QT) ncnt[tid] = 0;

    const float* qbase = Qp + ((size_t)bh * S_LEN + q0) * HD;
    const float* kbase = Kp + (size_t)bh * S_LEN * HD;
    const float* vbase = Vp + (size_t)bh * S_LEN * HD;

    // ---- Phase 1: Xa = (Q.K^T * scale * (alpha-1)) held in registers ----
    // One K row-chunk (8 floats, 8 VGPRs) live at a time; Q via SGPR s_loads.
    float xa[QT][4];
#pragma unroll
    for (int r = 0; r < QT; ++r)
#pragma unroll
        for (int kk = 0; kk < 4; ++kk) xa[r][kk] = 0.0f;

    for (int dc = 0; dc < 8; ++dc) {
#pragma unroll
        for (int kk = 0; kk < 4; ++kk) {
            const float* kptr = kbase + ((size_t)(kk * NT + tid)) * HD + dc * 8;
            float4 ka = *(const float4*)kptr;
            float4 kb4 = *(const float4*)(kptr + 4);
            float kb[8] = {ka.x, ka.y, ka.z, ka.w, kb4.x, kb4.y, kb4.z, kb4.w};
#pragma unroll
            for (int r = 0; r < QT; ++r) {
                const float* qp = qbase + r * HD + dc * 8;  // wave-uniform -> s_load
                float4 qa = *(const float4*)qp;
                float4 qb = *(const float4*)(qp + 4);
                float a0 = xa[r][kk];
                a0 = fmaf(qa.x, kb[0], a0);
                a0 = fmaf(qa.y, kb[1], a0);
                a0 = fmaf(qa.z, kb[2], a0);
                a0 = fmaf(qa.w, kb[3], a0);
                a0 = fmaf(qb.x, kb[4], a0);
                a0 = fmaf(qb.y, kb[5], a0);
                a0 = fmaf(qb.z, kb[6], a0);
                a0 = fmaf(qb.w, kb[7], a0);
                xa[r][kk] = a0;
            }
        }
    }
#pragma unroll
    for (int r = 0; r < QT; ++r)
#pragma unroll
        for (int kk = 0; kk < 4; ++kk) xa[r][kk] *= xscale;

    // ---- Phase 2: exact row maxes ----
#pragma unroll
    for (int r = 0; r < QT; ++r) {
        float pm = fmaxf(fmaxf(xa[r][0], xa[r][1]), fmaxf(xa[r][2], xa[r][3]));
        pm = wave_max(pm);
        if (lane == 0) rmax8[r][wv] = pm;
    }
    __syncthreads();
    if (tid < QT) {
        float m = rmax8[tid][0];
#pragma unroll
        for (int w = 1; w < NW; ++w) m = fmaxf(m, rmax8[tid][w]);
        rmxf[tid] = m;
    }
    __syncthreads();

    // ---- Phase 3: candidate compaction (Xa > tau_lo0 can ever be nonzero) ----
#pragma unroll
    for (int r = 0; r < QT; ++r) {
        const float tl0 = rmxf[r] - 1.0f;
#pragma unroll
        for (int kk = 0; kk < 4; ++kk) {
            const float v = xa[r][kk];
            const bool pred = (v > tl0);
            unsigned long long m = __ballot(pred);
            int base = 0;
            if (lane == 0 && m) base = atomicAdd(&ncnt[r], __popcll(m));
            base = __shfl(base, 0, 64);
            if (pred) {
                int pos = base + __popcll(m & ((1ull << lane) - 1ull));
                if (pos < CAP) {
                    candv[r][pos] = v;
                    candi[r][pos] = (unsigned short)(kk * NT + tid);
                }
            }
        }
    }
    __syncthreads();

    // ---- Phase 4: per-wave bisection (wave w owns row w; QT == NW) ----
    {
        const int row = wv;
        const int nc = ncnt[row];
        if (nc <= CAP) {
            const int ncp = (nc + 7) & ~7;
            for (int i = nc + lane; i < ncp; i += 64) {  // pad to multiple of 8
                candv[row][i] = -3.0e38f;
                candi[row][i] = 0;
            }
            const float mx  = rmxf[row];
            const float tl0 = mx - 1.0f;
            const float th  = mx - gp_d;
            float tau, isum;
            if (ncp <= 256) bisect_reg<4>(&candv[row][0], ncp, lane, tl0, th, inv, inv2, tau, isum);
            else            bisect_reg<8>(&candv[row][0], ncp, lane, tl0, th, inv, inv2, tau, isum);
            if (lane == 0) { taus[row] = tau; isums[row] = isum; }
        }
    }

    // ---- Phase 4b: block-wide fallback for overflow rows (nc > CAP; rare) ----
#pragma unroll
    for (int r = 0; r < QT; ++r) {
        if (ncnt[r] > CAP) {   // uniform condition -> barriers are safe
            const float mx = rmxf[r];
            float tau = mx - 1.0f;
            float s0 = 0.0f;
#pragma unroll
            for (int kk = 0; kk < 4; ++kk) s0 += pfun_t(xa[r][kk] - tau, inv, inv2);
            s0 = wave_sum(s0);
            if (lane == 0) redw[wv] = s0;
            __syncthreads();
            float f_lo = redw[0] + redw[1] + redw[2] + redw[3] +
                         redw[4] + redw[5] + redw[6] + redw[7] - 1.0f;
            __syncthreads();
            float dm = (mx - gp_d) - tau;
            for (int it = 0; it < NITER; ++it) {
                dm *= 0.5f;
                float tm = tau + dm;
                float s = 0.0f;
#pragma unroll
                for (int kk = 0; kk < 4; ++kk) s += pfun_t(xa[r][kk] - tm, inv, inv2);
                s = wave_sum(s);
                if (lane == 0) redw[wv] = s;
                __syncthreads();
                float fm = redw[0] + redw[1] + redw[2] + redw[3] +
                           redw[4] + redw[5] + redw[6] + redw[7] - 1.0f;
                __syncthreads();
                if (fm * f_lo >= 0.0f) tau = tm;
            }
            float s = 0.0f;
#pragma unroll
            for (int kk = 0; kk < 4; ++kk) s += pfun_t(xa[r][kk] - tau, inv, inv2);
            s = wave_sum(s);
            if (lane == 0) redw[wv] = s;
            __syncthreads();
            float ssum = redw[0] + redw[1] + redw[2] + redw[3] +
                         redw[4] + redw[5] + redw[6] + redw[7];
            __syncthreads();
            if (tid == 0) { taus[r] = tau; isums[r] = 1.0f / ssum; }
        }
    }
    __syncthreads();

    // ---- Phase 5: write normalized p_attn (all S entries incl. zeros) ----
    const size_t prow_base = ((size_t)bh * S_LEN + q0) * S_LEN;
#pragma unroll
    for (int r = 0; r < QT; ++r) {
        const float tau  = taus[r];
        const float isum = isums[r];
        float* prow = pattn + prow_base + (size_t)r * S_LEN;
#pragma unroll
        for (int kk = 0; kk < 4; ++kk) {
            float p = pfun_t(xa[r][kk] - tau, inv, inv2) * isum;
            prow[kk * NT + tid] = p;
        }
    }
    __threadfence_block();
    __syncthreads();

    // ---- Phase 6: out = p @ V, sparse over candidates (lane == d; QT == NW) ----
    {
        const int row  = wv;
        const int qrow = q0 + row;
        const int nc   = ncnt[row];
        const float tau  = taus[row];
        const float isum = isums[row];
        float oacc = 0.0f;
        if (nc <= CAP) {
            const int ncp = (nc + 7) & ~7;
            for (int i = lane; i < ncp; i += 64)  // candv := unnormalized p
                candv[row][i] = pfun_t(candv[row][i] - tau, inv, inv2);
            for (int i = 0; i < ncp; i += 8) {
#pragma unroll
                for (int u = 0; u < 8; ++u) {
                    oacc = fmaf(candv[row][i + u],
                                vbase[(size_t)candi[row][i + u] * HD + lane], oacc);
                }
            }
            oacc *= isum;
        } else {
            // read back normalized p from global (written above, fenced)
            const float* prow = pattn + ((size_t)bh * S_LEN + qrow) * S_LEN;
            for (int k = 0; k < S_LEN; ++k)
                oacc = fmaf(prow[k], vbase[(size_t)k * HD + lane], oacc);
        }
        outp[((size_t)bh * S_LEN + qrow) * HD + lane] = oacc;
    }
}

extern "C" void kernel_launch(void* const* d_in, const int* in_sizes, int n_in,
                              void* d_out, int out_size, void* d_ws, size_t ws_size,
                              hipStream_t stream) {
    const float* Q = (const float*)d_in[0];
    const float* K = (const float*)d_in[1];
    const float* V = (const float*)d_in[2];
    const float* A = (const float*)d_in[3];
    float* out = (float*)d_out;
    const int BH = in_sizes[0] / (S_LEN * HD);          // 64
    float* p = out + (size_t)BH * S_LEN * HD;           // p_attn follows out
    dim3 grid(S_LEN / QT, BH);
    entmax_attn<<<grid, NT, 0, stream>>>(Q, K, V, A, out, p);
}

// Round 4
// 2922.942 us; speedup vs baseline: 1.5280x; 1.2527x over previous
//
#include <hip/hip_runtime.h>
#include <math.h>

#define S_LEN 2048
#define HD    64
#define QT    16      // query rows per block (one 16-row MFMA tile)
#define NT    1024    // threads per block
#define NW    16      // waves per block
#define NTIL  8       // 16-col score tiles per wave (8*16*16 waves = 2048 cols)
#define CAP   512     // candidate capacity per row
#define NITER 28      // dm <= 2^-28: tau within 4e-9 of the 50-iter fp32 reference

typedef short s8v __attribute__((ext_vector_type(8)));   // 8 bf16 (4 VGPRs) MFMA A/B frag
typedef float f4v __attribute__((ext_vector_type(4)));   // MFMA C/D frag

__device__ __forceinline__ float wave_sum(float v) {
#pragma unroll
    for (int off = 32; off >= 1; off >>= 1)
        v += __shfl_xor(v, off, 64);
    return v;
}

__device__ __forceinline__ float group16_max(float v) {
#pragma unroll
    for (int off = 8; off >= 1; off >>= 1)
        v = fmaxf(v, __shfl_xor(v, off, 64));
    return v;
}

__device__ __forceinline__ unsigned f2bf2(float lo, float hi) {
    // two RNE float->bf16, packed into 32 bits
    unsigned a = __float_as_uint(lo), b = __float_as_uint(hi);
    a += 0x7FFFu + ((a >> 16) & 1u);
    b += 0x7FFFu + ((b >> 16) & 1u);
    return (a >> 16) | (b & 0xFFFF0000u);
}

__device__ __forceinline__ s8v pack_bf8(const float4& x, const float4& y, float sc) {
    union { s8v s; unsigned u[4]; } f;
    f.u[0] = f2bf2(x.x * sc, x.y * sc);
    f.u[1] = f2bf2(x.z * sc, x.w * sc);
    f.u[2] = f2bf2(y.x * sc, y.y * sc);
    f.u[3] = f2bf2(y.z * sc, y.w * sc);
    return f.s;
}

__device__ __forceinline__ float pfun_t(float t, float inv, bool inv2) {
    float u = fmaxf(t, 0.0f);
    return inv2 ? u * u : powf(u, inv);
}

// Register-resident bisection over <= NR*64 candidates held in LDS row cvrow.
template <int NR>
__device__ __forceinline__ void bisect_reg(const float* cvrow, int ncp, int lane,
                                           float tau_lo0, float tau_hi,
                                           float inv, bool inv2,
                                           float& tau_out, float& isum_out) {
    float c[NR];
#pragma unroll
    for (int j = 0; j < NR; ++j) {
        int i = lane + 64 * j;
        c[j] = (i < ncp) ? cvrow[i] : -3.0e38f;
    }
    float tau = tau_lo0;
    float s0 = 0.0f;
#pragma unroll
    for (int j = 0; j < NR; ++j) s0 += pfun_t(c[j] - tau, inv, inv2);
    const float f_lo = wave_sum(s0) - 1.0f;
    float dm = tau_hi - tau_lo0;
    for (int it = 0; it < NITER; ++it) {
        dm *= 0.5f;
        float tm = tau + dm;
        float s = 0.0f;
#pragma unroll
        for (int j = 0; j < NR; ++j) s += pfun_t(c[j] - tm, inv, inv2);
        float fm = wave_sum(s) - 1.0f;
        if (fm * f_lo >= 0.0f) tau = tm;
    }
    float s = 0.0f;
#pragma unroll
    for (int j = 0; j < NR; ++j) s += pfun_t(c[j] - tau, inv, inv2);
    float ssum = wave_sum(s);
    tau_out = tau;
    isum_out = 1.0f / ssum;
}

// bf16 MFMA QK^T. C/D layout (HW-verified m89): col=lane&15, row=(lane>>4)*4+reg.
// A/B frag: lane holds [m|n = lane&15][k = (lane>>4)*8 + j], j=0..7.
__global__ __launch_bounds__(NT)
void entmax_attn(const float* __restrict__ Qp, const float* __restrict__ Kp,
                 const float* __restrict__ Vp, const float* __restrict__ alphap,
                 float* __restrict__ outp, float* __restrict__ pattn) {
    __shared__ float          candv[QT][CAP];
    __shared__ unsigned short candi[QT][CAP];
    __shared__ int            ncnt[QT];
    __shared__ float          rmaxw[QT][NW];
    __shared__ float          rmxf[QT];
    __shared__ float          taus[QT];
    __shared__ float          isums[QT];
    __shared__ float          redw[NW];

    const int tid   = threadIdx.x;
    const int wv    = tid >> 6;
    const int lane  = tid & 63;
    const int quad  = lane >> 4;
    const int l16   = lane & 15;
    const int bh    = blockIdx.y;
    const int q0    = blockIdx.x * QT;
    const int wcol0 = wv * (NTIL * 16);    // 128 score cols per wave

    const float alpha = alphap[0];
    const float am1   = alpha - 1.0f;
    const float inv   = 1.0f / am1;
    const bool  inv2  = (inv == 2.0f);
    const float xscale = (1.0f / sqrtf((float)HD)) * am1;  // folded into Q before bf16
    const float gp_d   = powf(1.0f / (float)S_LEN, am1);

    if (tid < QT) ncnt[tid] = 0;

    const float* kbase = Kp + (size_t)bh * S_LEN * HD;
    const float* vbase = Vp + (size_t)bh * S_LEN * HD;

    // ---- Phase 1: Xa = (Q*xscale) @ K^T via MFMA, accumulators in regs ----
    s8v qa0, qa1;
    {
        const float* qp = Qp + ((size_t)bh * S_LEN + q0 + l16) * HD + quad * 8;
        float4 x0 = *(const float4*)qp;
        float4 x1 = *(const float4*)(qp + 4);
        float4 y0 = *(const float4*)(qp + 32);
        float4 y1 = *(const float4*)(qp + 36);
        qa0 = pack_bf8(x0, x1, xscale);   // k = 0..31 slice
        qa1 = pack_bf8(y0, y1, xscale);   // k = 32..63 slice
    }

    f4v xa[NTIL];
#pragma unroll
    for (int t = 0; t < NTIL; ++t) {
        const float* kp = kbase + ((size_t)(wcol0 + t * 16 + l16)) * HD + quad * 8;
        float4 k0 = *(const float4*)kp;
        float4 k1 = *(const float4*)(kp + 4);
        s8v kb0 = pack_bf8(k0, k1, 1.0f);
        f4v acc = {0.0f, 0.0f, 0.0f, 0.0f};
        acc = __builtin_amdgcn_mfma_f32_16x16x32_bf16(qa0, kb0, acc, 0, 0, 0);
        float4 k2 = *(const float4*)(kp + 32);
        float4 k3 = *(const float4*)(kp + 36);
        s8v kb1 = pack_bf8(k2, k3, 1.0f);
        acc = __builtin_amdgcn_mfma_f32_16x16x32_bf16(qa1, kb1, acc, 0, 0, 0);
        xa[t] = acc;
    }

    // ---- Phase 2: exact row maxes (row = quad*4+g within the Q tile) ----
#pragma unroll
    for (int g = 0; g < 4; ++g) {
        float pm = xa[0][g];
#pragma unroll
        for (int t = 1; t < NTIL; ++t) pm = fmaxf(pm, xa[t][g]);
        pm = group16_max(pm);
        if (l16 == 0) rmaxw[quad * 4 + g][wv] = pm;
    }
    __syncthreads();
    if (tid < QT) {
        float m = rmaxw[tid][0];
#pragma unroll
        for (int w = 1; w < NW; ++w) m = fmaxf(m, rmaxw[tid][w]);
        rmxf[tid] = m;
    }
    __syncthreads();

    // ---- Phase 3: candidate compaction (per-16-lane-group ballots) ----
    float tl0g[4];
#pragma unroll
    for (int g = 0; g < 4; ++g) tl0g[g] = rmxf[quad * 4 + g] - 1.0f;

#pragma unroll
    for (int t = 0; t < NTIL; ++t) {
#pragma unroll
        for (int g = 0; g < 4; ++g) {
            const float v = xa[t][g];
            const int row = quad * 4 + g;
            const bool pred = (v > tl0g[g]);
            unsigned long long m = __ballot(pred);
            unsigned gm16 = (unsigned)((m >> (quad * 16)) & 0xFFFFull);
            int base = 0;
            if (l16 == 0) {
                int cnt = __popc(gm16);
                if (cnt) base = atomicAdd(&ncnt[row], cnt);
            }
            base = __shfl(base, quad * 16, 64);
            if (pred) {
                int pos = base + __popc(gm16 & ((1u << l16) - 1u));
                if (pos < CAP) {
                    candv[row][pos] = v;
                    candi[row][pos] = (unsigned short)(wcol0 + t * 16 + l16);
                }
            }
        }
    }
    __syncthreads();

    // ---- Phase 4: per-wave bisection (wave w owns row w; QT == NW) ----
    {
        const int row = wv;
        const int nc = ncnt[row];
        if (nc <= CAP) {
            const int ncp = (nc + 7) & ~7;
            for (int i = nc + lane; i < ncp; i += 64) {  // pad to multiple of 8
                candv[row][i] = -3.0e38f;
                candi[row][i] = 0;
            }
            const float mx  = rmxf[row];
            const float tl0 = mx - 1.0f;
            const float th  = mx - gp_d;
            float tau, isum;
            if (ncp <= 256) bisect_reg<4>(&candv[row][0], ncp, lane, tl0, th, inv, inv2, tau, isum);
            else            bisect_reg<8>(&candv[row][0], ncp, lane, tl0, th, inv, inv2, tau, isum);
            if (lane == 0) { taus[row] = tau; isums[row] = isum; }
        }
    }

    // ---- Phase 4b: block-wide fallback for overflow rows (nc > CAP; rare) ----
#pragma unroll 1
    for (int r = 0; r < QT; ++r) {
        if (ncnt[r] > CAP) {   // uniform condition -> barriers are safe
            const float mx = rmxf[r];
            const int g = r & 3;
            const bool mine = (quad == (r >> 2));
            float tau = mx - 1.0f;
            float s0 = 0.0f;
            if (mine) {
#pragma unroll
                for (int t = 0; t < NTIL; ++t) s0 += pfun_t(xa[t][g] - tau, inv, inv2);
            }
            s0 = wave_sum(s0);
            if (lane == 0) redw[wv] = s0;
            __syncthreads();
            float f_lo = -1.0f;
            for (int w = 0; w < NW; ++w) f_lo += redw[w];
            __syncthreads();
            float dm = (mx - gp_d) - tau;
            for (int it = 0; it < NITER; ++it) {
                dm *= 0.5f;
                float tm = tau + dm;
                float s = 0.0f;
                if (mine) {
#pragma unroll
                    for (int t = 0; t < NTIL; ++t) s += pfun_t(xa[t][g] - tm, inv, inv2);
                }
                s = wave_sum(s);
                if (lane == 0) redw[wv] = s;
                __syncthreads();
                float fm = -1.0f;
                for (int w = 0; w < NW; ++w) fm += redw[w];
                __syncthreads();
                if (fm * f_lo >= 0.0f) tau = tm;
            }
            float s = 0.0f;
            if (mine) {
#pragma unroll
                for (int t = 0; t < NTIL; ++t) s += pfun_t(xa[t][g] - tau, inv, inv2);
            }
            s = wave_sum(s);
            if (lane == 0) redw[wv] = s;
            __syncthreads();
            float ssum = 0.0f;
            for (int w = 0; w < NW; ++w) ssum += redw[w];
            __syncthreads();
            if (tid == 0) { taus[r] = tau; isums[r] = 1.0f / ssum; }
        }
    }
    __syncthreads();

    // ---- Phase 5: write normalized p_attn (all S entries incl. zeros) ----
    const size_t prow_base = ((size_t)bh * S_LEN + q0) * S_LEN;
#pragma unroll
    for (int g = 0; g < 4; ++g) {
        const int row = quad * 4 + g;
        const float tau  = taus[row];
        const float isum = isums[row];
        float* prow = pattn + prow_base + (size_t)row * S_LEN + wcol0 + l16;
#pragma unroll
        for (int t = 0; t < NTIL; ++t) {
            prow[t * 16] = pfun_t(xa[t][g] - tau, inv, inv2) * isum;
        }
    }
    __threadfence_block();
    __syncthreads();

    // ---- Phase 6: out = p @ V, sparse over candidates (lane == d; QT == NW) ----
    {
        const int row  = wv;
        const int qrow = q0 + row;
        const int nc   = ncnt[row];
        const float tau  = taus[row];
        const float isum = isums[row];
        float oacc = 0.0f;
        if (nc <= CAP) {
            const int ncp = (nc + 7) & ~7;
            for (int i = lane; i < ncp; i += 64)  // candv := unnormalized p
                candv[row][i] = pfun_t(candv[row][i] - tau, inv, inv2);
            for (int i = 0; i < ncp; i += 8) {
#pragma unroll
                for (int u = 0; u < 8; ++u) {
                    oacc = fmaf(candv[row][i + u],
                                vbase[(size_t)candi[row][i + u] * HD + lane], oacc);
                }
            }
            oacc *= isum;
        } else {
            // read back normalized p from global (written above, fenced)
            const float* prow = pattn + ((size_t)bh * S_LEN + qrow) * S_LEN;
            for (int k = 0; k < S_LEN; ++k)
                oacc = fmaf(prow[k], vbase[(size_t)k * HD + lane], oacc);
        }
        outp[((size_t)bh * S_LEN + qrow) * HD + lane] = oacc;
    }
}

extern "C" void kernel_launch(void* const* d_in, const int* in_sizes, int n_in,
                              void* d_out, int out_size, void* d_ws, size_t ws_size,
                              hipStream_t stream) {
    const float* Q = (const float*)d_in[0];
    const float* K = (const float*)d_in[1];
    const float* V = (const float*)d_in[2];
    const float* A = (const float*)d_in[3];
    float* out = (float*)d_out;
    const int BH = in_sizes[0] / (S_LEN * HD);          // 64
    float* p = out + (size_t)BH * S_LEN * HD;           // p_attn follows out
    dim3 grid(S_LEN / QT, BH);
    entmax_attn<<<grid, NT, 0, stream>>>(Q, K, V, A, out, p);
}

// Round 5
// 2668.246 us; speedup vs baseline: 1.6739x; 1.0955x over previous
//
#include <hip/hip_runtime.h>
#include <math.h>

#define S_LEN 2048
#define HD    64
#define QT    16      // query rows per block (one 16-row MFMA tile)
#define NT    1024    // threads per block
#define NW    16      // waves per block
#define NTIL  8       // 16-col score tiles per wave (8*16*16 waves = 2048 cols)
#define CAP   512     // candidate capacity per row
#define NITER 28      // dm <= 2^-28: tau within 4e-9 of the 50-iter fp32 reference

typedef short s8v __attribute__((ext_vector_type(8)));   // 8 bf16 (4 VGPRs) MFMA A/B frag
typedef float f4v __attribute__((ext_vector_type(4)));   // MFMA C/D frag

template <bool B> struct BoolT { static constexpr bool value = B; };

__device__ __forceinline__ float wave_sum(float v) {
#pragma unroll
    for (int off = 32; off >= 1; off >>= 1)
        v += __shfl_xor(v, off, 64);
    return v;
}

__device__ __forceinline__ float group16_max(float v) {
#pragma unroll
    for (int off = 8; off >= 1; off >>= 1)
        v = fmaxf(v, __shfl_xor(v, off, 64));
    return v;
}

__device__ __forceinline__ unsigned f2bf2(float lo, float hi) {
    // two RNE float->bf16, packed into 32 bits
    unsigned a = __float_as_uint(lo), b = __float_as_uint(hi);
    a += 0x7FFFu + ((a >> 16) & 1u);
    b += 0x7FFFu + ((b >> 16) & 1u);
    return (a >> 16) | (b & 0xFFFF0000u);
}

__device__ __forceinline__ s8v pack_bf8(const float4& x, const float4& y, float sc) {
    union { s8v s; unsigned u[4]; } f;
    f.u[0] = f2bf2(x.x * sc, x.y * sc);
    f.u[1] = f2bf2(x.z * sc, x.w * sc);
    f.u[2] = f2bf2(y.x * sc, y.y * sc);
    f.u[3] = f2bf2(y.z * sc, y.w * sc);
    return f.s;
}

// INV2 is compile-time: alpha=1.5 path is u*u (3 VALU); runtime-bool version
// if-converted to ALWAYS evaluate powf (~25 VALU) -> was ~7000 VALU/thread (R4).
template <bool INV2>
__device__ __forceinline__ float pfun_t(float t, float inv) {
    float u = fmaxf(t, 0.0f);
    return INV2 ? u * u : powf(u, inv);
}

// Register-resident bisection over <= NR*64 candidates held in LDS row cvrow.
template <int NR, bool INV2>
__device__ __forceinline__ void bisect_reg(const float* cvrow, int ncp, int lane,
                                           float tau_lo0, float tau_hi, float inv,
                                           float& tau_out, float& isum_out) {
    float c[NR];
#pragma unroll
    for (int j = 0; j < NR; ++j) {
        int i = lane + 64 * j;
        c[j] = (i < ncp) ? cvrow[i] : -3.0e38f;
    }
    float tau = tau_lo0;
    float s0 = 0.0f;
#pragma unroll
    for (int j = 0; j < NR; ++j) s0 += pfun_t<INV2>(c[j] - tau, inv);
    const float f_lo = wave_sum(s0) - 1.0f;
    float dm = tau_hi - tau_lo0;
    for (int it = 0; it < NITER; ++it) {
        dm *= 0.5f;
        float tm = tau + dm;
        float s = 0.0f;
#pragma unroll
        for (int j = 0; j < NR; ++j) s += pfun_t<INV2>(c[j] - tm, inv);
        float fm = wave_sum(s) - 1.0f;
        if (fm * f_lo >= 0.0f) tau = tm;
    }
    float s = 0.0f;
#pragma unroll
    for (int j = 0; j < NR; ++j) s += pfun_t<INV2>(c[j] - tau, inv);
    float ssum = wave_sum(s);
    tau_out = tau;
    isum_out = 1.0f / ssum;
}

// bf16 MFMA QK^T. C/D layout (HW-verified m89): col=lane&15, row=(lane>>4)*4+reg.
// A/B frag: lane holds [m|n = lane&15][k = (lane>>4)*8 + j], j=0..7.
__global__ __launch_bounds__(NT)
void entmax_attn(const float* __restrict__ Qp, const float* __restrict__ Kp,
                 const float* __restrict__ Vp, const float* __restrict__ alphap,
                 float* __restrict__ outp, float* __restrict__ pattn) {
    __shared__ float          candv[QT][CAP];
    __shared__ unsigned short candi[QT][CAP];
    __shared__ int            ncnt[QT];
    __shared__ float          rmaxw[QT][NW];
    __shared__ float          rmxf[QT];
    __shared__ float          taus[QT];
    __shared__ float          isums[QT];
    __shared__ float          redw[NW];

    const int tid   = threadIdx.x;
    const int wv    = tid >> 6;
    const int lane  = tid & 63;
    const int quad  = lane >> 4;
    const int l16   = lane & 15;
    const int bh    = blockIdx.y;
    const int q0    = blockIdx.x * QT;
    const int wcol0 = wv * (NTIL * 16);    // 128 score cols per wave

    const float alpha = alphap[0];
    const float am1   = alpha - 1.0f;
    const float inv   = 1.0f / am1;
    const bool  inv2  = (inv == 2.0f);
    const float xscale = (1.0f / sqrtf((float)HD)) * am1;  // folded into Q before bf16
    const float gp_d   = powf(1.0f / (float)S_LEN, am1);

    if (tid < QT) ncnt[tid] = 0;

    const float* kbase = Kp + (size_t)bh * S_LEN * HD;
    const float* vbase = Vp + (size_t)bh * S_LEN * HD;

    // ---- Phase 1: Xa = (Q*xscale) @ K^T via MFMA, accumulators in regs ----
    s8v qa0, qa1;
    {
        const float* qp = Qp + ((size_t)bh * S_LEN + q0 + l16) * HD + quad * 8;
        float4 x0 = *(const float4*)qp;
        float4 x1 = *(const float4*)(qp + 4);
        float4 y0 = *(const float4*)(qp + 32);
        float4 y1 = *(const float4*)(qp + 36);
        qa0 = pack_bf8(x0, x1, xscale);   // k = 0..31 slice
        qa1 = pack_bf8(y0, y1, xscale);   // k = 32..63 slice
    }

    f4v xa[NTIL];
#pragma unroll
    for (int t = 0; t < NTIL; ++t) {
        const float* kp = kbase + ((size_t)(wcol0 + t * 16 + l16)) * HD + quad * 8;
        float4 k0 = *(const float4*)kp;
        float4 k1 = *(const float4*)(kp + 4);
        s8v kb0 = pack_bf8(k0, k1, 1.0f);
        f4v acc = {0.0f, 0.0f, 0.0f, 0.0f};
        acc = __builtin_amdgcn_mfma_f32_16x16x32_bf16(qa0, kb0, acc, 0, 0, 0);
        float4 k2 = *(const float4*)(kp + 32);
        float4 k3 = *(const float4*)(kp + 36);
        s8v kb1 = pack_bf8(k2, k3, 1.0f);
        acc = __builtin_amdgcn_mfma_f32_16x16x32_bf16(qa1, kb1, acc, 0, 0, 0);
        xa[t] = acc;
    }

    // ---- Phase 2: exact row maxes (row = quad*4+g within the Q tile) ----
#pragma unroll
    for (int g = 0; g < 4; ++g) {
        float pm = xa[0][g];
#pragma unroll
        for (int t = 1; t < NTIL; ++t) pm = fmaxf(pm, xa[t][g]);
        pm = group16_max(pm);
        if (l16 == 0) rmaxw[quad * 4 + g][wv] = pm;
    }
    __syncthreads();
    if (tid < QT) {
        float m = rmaxw[tid][0];
#pragma unroll
        for (int w = 1; w < NW; ++w) m = fmaxf(m, rmaxw[tid][w]);
        rmxf[tid] = m;
    }
    __syncthreads();

    // ---- Phase 3: candidate compaction (per-16-lane-group ballots) ----
    float tl0g[4];
#pragma unroll
    for (int g = 0; g < 4; ++g) tl0g[g] = rmxf[quad * 4 + g] - 1.0f;

#pragma unroll
    for (int t = 0; t < NTIL; ++t) {
#pragma unroll
        for (int g = 0; g < 4; ++g) {
            const float v = xa[t][g];
            const int row = quad * 4 + g;
            const bool pred = (v > tl0g[g]);
            unsigned long long m = __ballot(pred);
            unsigned gm16 = (unsigned)((m >> (quad * 16)) & 0xFFFFull);
            int base = 0;
            if (l16 == 0) {
                int cnt = __popc(gm16);
                if (cnt) base = atomicAdd(&ncnt[row], cnt);
            }
            base = __shfl(base, quad * 16, 64);
            if (pred) {
                int pos = base + __popc(gm16 & ((1u << l16) - 1u));
                if (pos < CAP) {
                    candv[row][pos] = v;
                    candi[row][pos] = (unsigned short)(wcol0 + t * 16 + l16);
                }
            }
        }
    }
    __syncthreads();

    // ---- Tail phases, specialized on INV2 (block-uniform branch) ----
    auto tail = [&](auto inv2c) {
        constexpr bool INV2 = decltype(inv2c)::value;

        // Phase 4: per-wave bisection (wave w owns row w; QT == NW)
        {
            const int row = wv;
            const int nc = ncnt[row];
            if (nc <= CAP) {
                const int ncp = (nc + 7) & ~7;
                for (int i = nc + lane; i < ncp; i += 64) {  // pad to multiple of 8
                    candv[row][i] = -3.0e38f;
                    candi[row][i] = 0;
                }
                const float mx  = rmxf[row];
                const float tl0 = mx - 1.0f;
                const float th  = mx - gp_d;
                float tau, isum;
                if (ncp <= 256) bisect_reg<4, INV2>(&candv[row][0], ncp, lane, tl0, th, inv, tau, isum);
                else            bisect_reg<8, INV2>(&candv[row][0], ncp, lane, tl0, th, inv, tau, isum);
                if (lane == 0) { taus[row] = tau; isums[row] = isum; }
            }
        }

        // Phase 4b: block-wide fallback for overflow rows (nc > CAP; rare)
#pragma unroll 1
        for (int r = 0; r < QT; ++r) {
            if (ncnt[r] > CAP) {   // uniform condition -> barriers are safe
                const float mx = rmxf[r];
                const int g = r & 3;
                const bool mine = (quad == (r >> 2));
                float tau = mx - 1.0f;
                float s0 = 0.0f;
                if (mine) {
#pragma unroll
                    for (int t = 0; t < NTIL; ++t) s0 += pfun_t<INV2>(xa[t][g] - tau, inv);
                }
                s0 = wave_sum(s0);
                if (lane == 0) redw[wv] = s0;
                __syncthreads();
                float f_lo = -1.0f;
                for (int w = 0; w < NW; ++w) f_lo += redw[w];
                __syncthreads();
                float dm = (mx - gp_d) - tau;
                for (int it = 0; it < NITER; ++it) {
                    dm *= 0.5f;
                    float tm = tau + dm;
                    float s = 0.0f;
                    if (mine) {
#pragma unroll
                        for (int t = 0; t < NTIL; ++t) s += pfun_t<INV2>(xa[t][g] - tm, inv);
                    }
                    s = wave_sum(s);
                    if (lane == 0) redw[wv] = s;
                    __syncthreads();
                    float fm = -1.0f;
                    for (int w = 0; w < NW; ++w) fm += redw[w];
                    __syncthreads();
                    if (fm * f_lo >= 0.0f) tau = tm;
                }
                float s = 0.0f;
                if (mine) {
#pragma unroll
                    for (int t = 0; t < NTIL; ++t) s += pfun_t<INV2>(xa[t][g] - tau, inv);
                }
                s = wave_sum(s);
                if (lane == 0) redw[wv] = s;
                __syncthreads();
                float ssum = 0.0f;
                for (int w = 0; w < NW; ++w) ssum += redw[w];
                __syncthreads();
                if (tid == 0) { taus[r] = tau; isums[r] = 1.0f / ssum; }
            }
        }
        __syncthreads();

        // Phase 5: write normalized p_attn (all S entries incl. zeros)
        const size_t prow_base = ((size_t)bh * S_LEN + q0) * S_LEN;
#pragma unroll
        for (int g = 0; g < 4; ++g) {
            const int row = quad * 4 + g;
            const float tau  = taus[row];
            const float isum = isums[row];
            float* prow = pattn + prow_base + (size_t)row * S_LEN + wcol0 + l16;
#pragma unroll
            for (int t = 0; t < NTIL; ++t) {
                prow[t * 16] = pfun_t<INV2>(xa[t][g] - tau, inv) * isum;
            }
        }
        __threadfence_block();
        __syncthreads();

        // Phase 6: out = p @ V, sparse over candidates (lane == d; QT == NW)
        {
            const int row  = wv;
            const int qrow = q0 + row;
            const int nc   = ncnt[row];
            const float tau  = taus[row];
            const float isum = isums[row];
            float oacc = 0.0f;
            if (nc <= CAP) {
                const int ncp = (nc + 7) & ~7;
                for (int i = lane; i < ncp; i += 64)  // candv := unnormalized p
                    candv[row][i] = pfun_t<INV2>(candv[row][i] - tau, inv);
                for (int i = 0; i < ncp; i += 8) {
#pragma unroll
                    for (int u = 0; u < 8; ++u) {
                        oacc = fmaf(candv[row][i + u],
                                    vbase[(size_t)candi[row][i + u] * HD + lane], oacc);
                    }
                }
                oacc *= isum;
            } else {
                // read back normalized p from global (written above, fenced)
                const float* prow = pattn + ((size_t)bh * S_LEN + qrow) * S_LEN;
                for (int k = 0; k < S_LEN; ++k)
                    oacc = fmaf(prow[k], vbase[(size_t)k * HD + lane], oacc);
            }
            outp[((size_t)bh * S_LEN + qrow) * HD + lane] = oacc;
        }
    };

    if (inv2) tail(BoolT<true>{});   // alpha == 1.5 fast path (u*u)
    else      tail(BoolT<false>{});  // generic alpha (powf)
}

extern "C" void kernel_launch(void* const* d_in, const int* in_sizes, int n_in,
                              void* d_out, int out_size, void* d_ws, size_t ws_size,
                              hipStream_t stream) {
    const float* Q = (const float*)d_in[0];
    const float* K = (const float*)d_in[1];
    const float* V = (const float*)d_in[2];
    const float* A = (const float*)d_in[3];
    float* out = (float*)d_out;
    const int BH = in_sizes[0] / (S_LEN * HD);          // 64
    float* p = out + (size_t)BH * S_LEN * HD;           // p_attn follows out
    dim3 grid(S_LEN / QT, BH);
    entmax_attn<<<grid, NT, 0, stream>>>(Q, K, V, A, out, p);
}